// Round 2
// baseline (37.441 us; speedup 1.0000x reference)
//
#include <hip/hip_runtime.h>
#include <math.h>

// Problem constants (from the reference)
#define NBATCH 16384
#define NJOINT 32
#define MIN_TH2 0.25f   // 0.5^2
#define MAX_TH2 4.0f    // 2.0^2

#define BATCHES_PER_BLOCK 8
#define BLOCK 256                                  // 8 batches * 32 joints
#define NBLK (NBATCH / BATCHES_PER_BLOCK)          // 2048
#define FLOATS_PER_BLOCK (BATCHES_PER_BLOCK * NJOINT * 3)  // 768

// Packed-atomic layout in d_ws[0] (uint64):
//   bits [0:12)  : completion counter (2048 blocks, fits in 12 bits)
//   bits [12:64) : fixed-point sum, scale 2^20
//     total float sum ~4.4e7 -> 4.6e13 fixed units << 2^52. Quantization
//     error <= 2048 * 2^-21 ~= 1e-3 absolute on the sum -> negligible vs
//     the 0.4775 absmax threshold.
#define FIX_SCALE 1048576.0f   // 2^20
#define CNT_BITS 12
#define CNT_MASK 0xFFFULL

__global__ void __launch_bounds__(BLOCK) sep_loss_fused(
        const float* __restrict__ kps,
        unsigned long long* __restrict__ ws,
        float* __restrict__ out) {
    __shared__ float lds[FLOATS_PER_BLOCK];   // 3 KB
    __shared__ float wsum[BLOCK / 64];        // per-wave partial sums

    const int tid = threadIdx.x;
    const long long base = (long long)blockIdx.x * FLOATS_PER_BLOCK;

    // Coalesced float4 stage: 768 floats = 192 float4.
    if (tid < FLOATS_PER_BLOCK / 4)
        ((float4*)lds)[tid] = ((const float4*)(kps + base))[tid];
    __syncthreads();

    const int b_local = tid >> 5;   // 0..7  : batch item within block
    const int i       = tid & 31;   // 0..31 : joint this thread owns
    const float* jb = &lds[b_local * (NJOINT * 3)];

    const float xi = jb[i * 3 + 0];
    const float yi = jb[i * 3 + 1];
    const float zi = jb[i * 3 + 2];

    float acc = 0.0f;
    #pragma unroll
    for (int j = 0; j < NJOINT; ++j) {
        const float dx = xi - jb[j * 3 + 0];
        const float dy = yi - jb[j * 3 + 1];
        const float dz = zi - jb[j * 3 + 2];
        const float d2 = dx * dx + dy * dy + dz * dz;
        float pen = fmaxf(0.0f, MIN_TH2 - d2) + fmaxf(0.0f, d2 - MAX_TH2);
        if (j == i) pen = 0.0f;     // exclude diagonal (d2=0 would add MIN_TH2)
        acc += pen;
    }

    // Wave (64-lane) shuffle reduce.
    #pragma unroll
    for (int off = 32; off > 0; off >>= 1)
        acc += __shfl_down(acc, off, 64);

    const int wave = tid >> 6;       // 0..3
    if ((tid & 63) == 0) wsum[wave] = acc;
    __syncthreads();

    if (tid == 0) {
        const float block_partial = wsum[0] + wsum[1] + wsum[2] + wsum[3];
        const unsigned long long my_fixed =
            (unsigned long long)llrintf(block_partial * FIX_SCALE);
        const unsigned long long pack = (my_fixed << CNT_BITS) | 1ULL;
        // Device-scope atomic: delivers the partial AND the completion tick
        // in one operation -> no separate fence needed, exactly commutative
        // integer adds -> deterministic.
        const unsigned long long old = atomicAdd(ws, pack);
        if ((old & CNT_MASK) + 1ULL == (unsigned long long)NBLK) {
            const unsigned long long total_fixed = (old >> CNT_BITS) + my_fixed;
            const float total = (float)((double)total_fixed / (double)FIX_SCALE);
            const float mean = total / (float)NBATCH;
            out[0] = powf(mean, 0.4f);
        }
    }
}

extern "C" void kernel_launch(void* const* d_in, const int* in_sizes, int n_in,
                              void* d_out, int out_size, void* d_ws, size_t ws_size,
                              hipStream_t stream) {
    const float* kps = (const float*)d_in[0];
    float* out = (float*)d_out;
    unsigned long long* ws = (unsigned long long*)d_ws;

    // Zero the packed accumulator each call (graph-capturable memset node).
    hipMemsetAsync(ws, 0, sizeof(unsigned long long), stream);
    sep_loss_fused<<<NBLK, BLOCK, 0, stream>>>(kps, ws, out);
}